// Round 9
// baseline (1421.972 us; speedup 1.0000x reference)
//
#include <hip/hip_runtime.h>
#include <hip/hip_bf16.h>

#define NN 50000
#define EE 800000
#define TT 4
#define NPAD 50048         // 391*128, padded row count for async-LDS A loads
#define SCAN_NB 49         // ceil(50000/1024)
#define PROP_NG 1563       // ceil(50000/32)
#define DEGB 64            // degree buckets for counting sort

typedef __hip_bfloat16 bf16;
typedef short bf16x8 __attribute__((ext_vector_type(8)));
typedef float f32x4 __attribute__((ext_vector_type(4)));

__device__ __forceinline__ void async_copy16(const void* g, void* l) {
  __builtin_amdgcn_global_load_lds((const __attribute__((address_space(1))) unsigned int*)g,
                                   (__attribute__((address_space(3))) unsigned int*)l,
                                   16, 0, 0);
}

__device__ __forceinline__ float b2f(short s) {
  return __uint_as_float(((unsigned)(unsigned short)s) << 16);
}

// fast sigmoid/tanh via v_exp_f32 (2^x) + v_rcp_f32.
// Saturation is clean: exp2->inf => rcp->0 (sig=0/tanh=-1); exp2->0 => rcp(1)=1.
__device__ __forceinline__ float fsig(float x) {
  float e = __builtin_amdgcn_exp2f(x * -1.442695041f);
  return __builtin_amdgcn_rcpf(1.f + e);
}
__device__ __forceinline__ float ftanh(float x) {
  float e = __builtin_amdgcn_exp2f(x * -2.885390082f);
  return fmaf(2.f, __builtin_amdgcn_rcpf(1.f + e), -1.f);
}

// ---------------- prep: W_allT [512][768] bf16, fused bias[512] fp32, Wpool bf16 ----------------
__global__ void prep_kernel(const float* __restrict__ convW, const float* __restrict__ convB,
                            const float* __restrict__ gateB, const float* __restrict__ Wpool,
                            bf16* __restrict__ WallT, float* __restrict__ bias,
                            bf16* __restrict__ WpoolBf) {
  int idx = blockIdx.x * 256 + threadIdx.x;
  if (idx < 512 * 768) {
    int nn = idx / 768, k = idx % 768;
    int g = nn >> 7, c = nn & 127;
    int xh = (k >= 384) ? 1 : 0;
    int k2 = k - xh * 384;
    int kch = k2 >> 7, r = k2 & 127;
    WallT[idx] = __float2bfloat16(convW[(((2 * g + xh) * 3 + kch) * 128 + r) * 128 + c]);
  } else if (idx < 512 * 768 + 512) {
    int n2 = idx - 512 * 768;
    int g = n2 >> 7, c = n2 & 127;
    bias[n2] = convB[(2 * g) * 128 + c] + convB[(2 * g + 1) * 128 + c] + gateB[g * 128 + c];
  } else if (idx < 512 * 768 + 512 + 128 * 128) {
    int n3 = idx - (512 * 768 + 512);
    WpoolBf[n3] = __float2bfloat16(Wpool[n3]);
  }
}

// ---------------- graph preprocessing ----------------
__global__ void degcount_kernel(const int* __restrict__ src, const int* __restrict__ dst,
                                float* __restrict__ deg, int* __restrict__ counts) {
  int e = blockIdx.x * 256 + threadIdx.x;
  if (e < EE) {
    atomicAdd(&deg[src[e]], 1.0f);
    atomicAdd(&counts[dst[e]], 1);
  }
}

__global__ void dinv_kernel(float* deg) {
  int n = blockIdx.x * 256 + threadIdx.x;
  if (n < NN) {
    float d = deg[n];
    deg[n] = (d > 0.f) ? rsqrtf(d) : 0.f;
  }
}

// partial sums: block b sums counts[b*1024 .. b*1024+1023]
__global__ void blocksum_kernel(const int* __restrict__ counts, int* __restrict__ bsum) {
  __shared__ int wsum2[4];
  int b = blockIdx.x, tid = threadIdx.x;
  int v = 0;
#pragma unroll
  for (int i = 0; i < 4; ++i) {
    int idx = b * 1024 + tid + i * 256;
    v += (idx < NN) ? counts[idx] : 0;
  }
#pragma unroll
  for (int off = 32; off; off >>= 1) v += __shfl_down(v, off);
  if ((tid & 63) == 0) wsum2[tid >> 6] = v;
  __syncthreads();
  if (tid == 0) bsum[b] = wsum2[0] + wsum2[1] + wsum2[2] + wsum2[3];
}

// full scan: each block re-reads the 49 block sums, scans its own 1024 chunk
__global__ void scan2_kernel(const int* __restrict__ counts, const int* __restrict__ bsum,
                             int* __restrict__ row_ptr, int* __restrict__ cursor) {
  __shared__ int wsum[16];
  int b = blockIdx.x, tid = threadIdx.x;
  int lane = tid & 63, wv = tid >> 6;
  int boff = 0, total = 0;
  for (int i = 0; i < SCAN_NB; ++i) {
    int s = bsum[i];
    if (i < b) boff += s;
    total += s;
  }
  int idx = b * 1024 + tid;
  int v = (idx < NN) ? counts[idx] : 0;
  int sc = v;
#pragma unroll
  for (int off = 1; off < 64; off <<= 1) {
    int t = __shfl_up(sc, off);
    if (lane >= off) sc += t;
  }
  if (lane == 63) wsum[wv] = sc;
  __syncthreads();
  if (wv == 0) {
    int w = (lane < 16) ? wsum[lane] : 0;
#pragma unroll
    for (int off = 1; off < 16; off <<= 1) {
      int t = __shfl_up(w, off);
      if (lane >= off) w += t;
    }
    if (lane < 16) wsum[lane] = w;
  }
  __syncthreads();
  int excl = boff + sc - v + (wv ? wsum[wv - 1] : 0);
  if (idx < NN) { row_ptr[idx] = excl; cursor[idx] = excl; }
  if (b == 0 && tid == 0) row_ptr[NN] = total;
}

// pack (src, weight) per edge into uint2
__global__ void fill_kernel(const int* __restrict__ src, const int* __restrict__ dst,
                            const float* __restrict__ dinv, int* __restrict__ cursor,
                            uint2* __restrict__ edata) {
  int e = blockIdx.x * 256 + threadIdx.x;
  if (e < EE) {
    int s = src[e], d = dst[e];
    float w = -(dinv[s] * dinv[d]);
    int pos = atomicAdd(&cursor[d], 1);
    uint2 v;
    v.x = (unsigned)s;
    v.y = __float_as_uint(w);
    edata[pos] = v;
  }
}

// ---- degree-uniform node permutation (counting sort by in-degree, descending) ----
// prop waves run 8 nodes in lockstep: cost = max(8 degrees) ~ 22 for Poisson(16)
// vs mean 16 -> ~27% masked-idle. Sorting nodes by degree makes each wave's 8
// groups degree-uniform (cost ~ mean), and puts heavy blocks first (tail).
// ZERO extra workspace: perm overlays cursor (dead after fill_kernel; scan2
// fully rewrites it each graph replay); hist/rankc overlay the head of G
// (first written by the big GEMM inside the t-loop, after degfill is done).
__global__ void deghist_kernel(const int* __restrict__ counts, int* __restrict__ hist) {
  int n = blockIdx.x * 256 + threadIdx.x;
  if (n < NN) {
    int d = counts[n]; if (d > DEGB - 1) d = DEGB - 1;
    atomicAdd(&hist[d], 1);
  }
}
__global__ void degfill_kernel(const int* __restrict__ counts, const int* __restrict__ hist,
                               int* __restrict__ rankc, int* __restrict__ perm) {
  int n = blockIdx.x * 256 + threadIdx.x;
  if (n < NN) {
    int d = counts[n]; if (d > DEGB - 1) d = DEGB - 1;
    int base = 0;
    for (int e = d + 1; e < DEGB; ++e) base += hist[e];  // 64 hot ints, L2 broadcast
    int r = atomicAdd(&rankc[d], 1);
    perm[base + r] = n;
  }
}

// zero the H window Z[:,384:512)
__global__ void zeroH_kernel(bf16* __restrict__ Z) {
  int i = blockIdx.x * 256 + threadIdx.x;
  if (i < NN * 16) {
    int n = i >> 4, c = i & 15;
    *(uint4*)(Z + (size_t)n * 768 + 384 + c * 8) = make_uint4(0u, 0u, 0u, 0u);
  }
}

// ---------------- prop: out = scale * (P @ in) - base ----------------
__device__ __forceinline__ void accum8(float* acc, uint4 z, float w) {
  float f0 = __uint_as_float(z.x << 16);
  float f1 = __uint_as_float(z.x & 0xffff0000u);
  float f2 = __uint_as_float(z.y << 16);
  float f3 = __uint_as_float(z.y & 0xffff0000u);
  float f4 = __uint_as_float(z.z << 16);
  float f5 = __uint_as_float(z.z & 0xffff0000u);
  float f6 = __uint_as_float(z.w << 16);
  float f7 = __uint_as_float(z.w & 0xffff0000u);
  acc[0] = fmaf(w, f0, acc[0]);
  acc[1] = fmaf(w, f1, acc[1]);
  acc[2] = fmaf(w, f2, acc[2]);
  acc[3] = fmaf(w, f3, acc[3]);
  acc[4] = fmaf(w, f4, acc[4]);
  acc[5] = fmaf(w, f5, acc[5]);
  acc[6] = fmaf(w, f6, acc[6]);
  acc[7] = fmaf(w, f7, acc[7]);
}

// Half-split prop (proven form): subtask = bid&3 = (window, 64ch-half).
// 8 lanes x 16B = 128B per edge gather = one full L2 line per request.
// Nodes are taken through the degree-sorted perm -> degree-uniform waves.
// Per-node results bit-identical (row-internal edge order unchanged); writes
// and base reads were already 128B scatters (row stride 1536B), so no loss.
__global__ __launch_bounds__(256) void prop_half(const int* __restrict__ row_ptr,
                                                 const uint2* __restrict__ edata,
                                                 const int* __restrict__ perm,
                                                 bf16* __restrict__ Z,
                                                 int in_offA, int out_offA, int baseA,
                                                 int in_offB, int out_offB, int baseB,
                                                 float scale) {
  const int bid = blockIdx.x;
  const int st = bid & 3;
  const int half = st & 1;
  const int grp = st >> 1;
  const int in_off  = (grp ? in_offB  : in_offA) + half * 64;
  const int out_off = (grp ? out_offB : out_offA) + half * 64;
  const int base    = grp ? baseB : baseA;
  const int tid = threadIdx.x;
  const int idx = (bid >> 2) * 32 + (tid >> 3);
  const int lane = tid & 7;
  if (idx >= NN) return;
  const int node = perm[idx];
  const int e0 = row_ptr[node], e1 = row_ptr[node + 1];
  float acc[8] = {0.f, 0.f, 0.f, 0.f, 0.f, 0.f, 0.f, 0.f};
  const bf16* zin = Z + in_off + lane * 8;
  int e = e0;
  for (; e + 4 <= e1; e += 4) {
    uint2 d0 = edata[e];
    uint2 d1 = edata[e + 1];
    uint2 d2 = edata[e + 2];
    uint2 d3 = edata[e + 3];
    uint4 z0 = *(const uint4*)(zin + (size_t)d0.x * 768);
    uint4 z1 = *(const uint4*)(zin + (size_t)d1.x * 768);
    uint4 z2 = *(const uint4*)(zin + (size_t)d2.x * 768);
    uint4 z3 = *(const uint4*)(zin + (size_t)d3.x * 768);
    accum8(acc, z0, __uint_as_float(d0.y));
    accum8(acc, z1, __uint_as_float(d1.y));
    accum8(acc, z2, __uint_as_float(d2.y));
    accum8(acc, z3, __uint_as_float(d3.y));
  }
  for (; e < e1; ++e) {
    uint2 d = edata[e];
    uint4 z = *(const uint4*)(zin + (size_t)d.x * 768);
    accum8(acc, z, __uint_as_float(d.y));
  }
  float bv[8] = {0.f, 0.f, 0.f, 0.f, 0.f, 0.f, 0.f, 0.f};
  if (base >= 0) {
    uint4 b = *(const uint4*)(Z + (size_t)node * 768 + base + half * 64 + lane * 8);
    bv[0] = __uint_as_float(b.x << 16);
    bv[1] = __uint_as_float(b.x & 0xffff0000u);
    bv[2] = __uint_as_float(b.y << 16);
    bv[3] = __uint_as_float(b.y & 0xffff0000u);
    bv[4] = __uint_as_float(b.z << 16);
    bv[5] = __uint_as_float(b.z & 0xffff0000u);
    bv[6] = __uint_as_float(b.w << 16);
    bv[7] = __uint_as_float(b.w & 0xffff0000u);
  }
  union {
    bf16 h[8];
    uint4 v;
  } o;
#pragma unroll
  for (int j = 0; j < 8; ++j)
    o.h[j] = __float2bfloat16(fmaf(scale, acc[j], -bv[j]));
  *(uint4*)(Z + (size_t)node * 768 + out_off + lane * 8) = o.v;
}

// ---------------- GEMM: C[M,Nc] = A[M,K] @ Bt[Nc,K]^T, fp32 acc ----------------
// 2-PHASE double-buffered (T3 minimum recipe): stage tile it+1 into buf^1
// BEFORE computing tile it from buf; ONE __syncthreads per K-step.
// Measured r5: 79us, MfmaUtil 19%, VALUBusy 15% -- barrier-drain structural
// ceiling of the 2-barrier family; next step would be the 8-phase rewrite.
// Flat LDS tiles (128 rows x 32 bf16), XOR-swizzled 16B chunks:
// chunk (row r, kseg s) at chunk index r*4 + (s ^ ((r>>1)&3)).
template <int A_FP32>
__global__ __launch_bounds__(256) void gemm_bt(const void* __restrict__ Ain, int lda,
                                               const bf16* __restrict__ Bt, int ldbt,
                                               bf16* __restrict__ Cout, int ldc,
                                               int M, int K) {
  __shared__ __align__(16) bf16 As[2][128 * 32];
  __shared__ __align__(16) bf16 Bs[2][128 * 32];
  const int tid = threadIdx.x;
  const int lane = tid & 63, wid = tid >> 6;
  const int wm = wid >> 1, wn = wid & 1;
  const int m_base = blockIdx.x * 128;
  const int n_base = blockIdx.y * 128;
  f32x4 acc[4][4] = {};

  // staging chunks c0 = tid, c1 = tid + 256; r = c>>2, p = c&3, s = p ^ ((r>>1)&3)
  const int r0 = tid >> 2, p = tid & 3;
  const int r1 = r0 + 64;
  const int s0 = p ^ ((r0 >> 1) & 3);
  const int s1 = p ^ ((r1 >> 1) & 3);

  const bf16* Ag0 = (const bf16*)Ain + (size_t)(m_base + r0) * lda + s0 * 8;
  const bf16* Ag1 = (const bf16*)Ain + (size_t)(m_base + r1) * lda + s1 * 8;
  const float* Af0 = (const float*)Ain + (size_t)(m_base + r0) * lda + s0 * 8;
  const float* Af1 = (const float*)Ain + (size_t)(m_base + r1) * lda + s1 * 8;
  const bf16* Bg0 = Bt + (size_t)(n_base + r0) * ldbt + s0 * 8;
  const bf16* Bg1 = Bt + (size_t)(n_base + r1) * ldbt + s1 * 8;

  const bool row0ok = (m_base + r0 < M);
  const bool row1ok = (m_base + r1 < M);

  // async stagers (wave-uniform LDS base + lane*16 per global_load_lds rules)
  auto stageA_async = [&](bf16* dst) {
    async_copy16(Ag0, dst + wid * 512);
    async_copy16(Ag1, dst + 2048 + wid * 512);
    Ag0 += 32; Ag1 += 32;
  };
  auto stageB = [&](bf16* dst) {
    async_copy16(Bg0, dst + wid * 512);
    async_copy16(Bg1, dst + 2048 + wid * 512);
    Bg0 += 32; Bg1 += 32;
  };
  auto writeA_fp32 = [&](bf16* dst, float4 f0, float4 f1, float4 f2, float4 f3) {
    bf16 tmp[8];
    tmp[0] = __float2bfloat16(f0.x); tmp[1] = __float2bfloat16(f0.y);
    tmp[2] = __float2bfloat16(f0.z); tmp[3] = __float2bfloat16(f0.w);
    tmp[4] = __float2bfloat16(f1.x); tmp[5] = __float2bfloat16(f1.y);
    tmp[6] = __float2bfloat16(f1.z); tmp[7] = __float2bfloat16(f1.w);
    *(uint4*)(dst + tid * 8) = *(const uint4*)tmp;
    tmp[0] = __float2bfloat16(f2.x); tmp[1] = __float2bfloat16(f2.y);
    tmp[2] = __float2bfloat16(f2.z); tmp[3] = __float2bfloat16(f2.w);
    tmp[4] = __float2bfloat16(f3.x); tmp[5] = __float2bfloat16(f3.y);
    tmp[6] = __float2bfloat16(f3.z); tmp[7] = __float2bfloat16(f3.w);
    *(uint4*)(dst + (tid + 256) * 8) = *(const uint4*)tmp;
  };

  // fragment LDS elem offsets, fixed per lane
  int offA[4], offB[4];
  const int sq = lane >> 4;
#pragma unroll
  for (int tm = 0; tm < 4; ++tm) {
    int r = wm * 64 + tm * 16 + (lane & 15);
    offA[tm] = r * 32 + (sq ^ ((r >> 1) & 3)) * 8;
  }
#pragma unroll
  for (int tn = 0; tn < 4; ++tn) {
    int r = wn * 64 + tn * 16 + (lane & 15);
    offB[tn] = r * 32 + (sq ^ ((r >> 1) & 3)) * 8;
  }

  const int nk = K >> 5;

  // prologue: stage tile 0 into buffer 0
  if (A_FP32) {
    float4 f0 = make_float4(0.f, 0.f, 0.f, 0.f), f1 = f0, f2 = f0, f3 = f0;
    if (row0ok) { f0 = *(const float4*)Af0; f1 = *(const float4*)(Af0 + 4); }
    if (row1ok) { f2 = *(const float4*)Af1; f3 = *(const float4*)(Af1 + 4); }
    Af0 += 32; Af1 += 32;
    writeA_fp32(As[0], f0, f1, f2, f3);
  } else {
    stageA_async(As[0]);
  }
  stageB(Bs[0]);
  __syncthreads();

  for (int it = 0; it < nk; ++it) {
    const bf16* Ac = As[it & 1];
    const bf16* Bc = Bs[it & 1];
    bf16* An = As[(it + 1) & 1];
    bf16* Bn = Bs[(it + 1) & 1];
    const bool pre = (it + 1 < nk);

    // issue next-tile loads first (latency hides under ds_read + MFMA)
    float4 f0 = make_float4(0.f, 0.f, 0.f, 0.f), f1 = f0, f2 = f0, f3 = f0;
    if (pre) {
      if (A_FP32) {
        if (row0ok) { f0 = *(const float4*)Af0; f1 = *(const float4*)(Af0 + 4); }
        if (row1ok) { f2 = *(const float4*)Af1; f3 = *(const float4*)(Af1 + 4); }
        Af0 += 32; Af1 += 32;
      } else {
        stageA_async(An);
      }
      stageB(Bn);
    }

    bf16x8 af[4], bfr[4];
#pragma unroll
    for (int tm = 0; tm < 4; ++tm) af[tm] = *(const bf16x8*)(Ac + offA[tm]);
#pragma unroll
    for (int tn = 0; tn < 4; ++tn) bfr[tn] = *(const bf16x8*)(Bc + offB[tn]);
#pragma unroll
    for (int tm = 0; tm < 4; ++tm)
#pragma unroll
      for (int tn = 0; tn < 4; ++tn)
        acc[tm][tn] = __builtin_amdgcn_mfma_f32_16x16x32_bf16(af[tm], bfr[tn], acc[tm][tn], 0, 0, 0);

    // late LDS write for the fp32-A path (regs were loaded early, T14 split)
    if (pre && A_FP32) writeA_fp32(An, f0, f1, f2, f3);

    __syncthreads();
  }

  // C/D layout: col = lane&15, row = (lane>>4)*4 + i  [m89/m91 verified]
#pragma unroll
  for (int tm = 0; tm < 4; ++tm) {
#pragma unroll
    for (int tn = 0; tn < 4; ++tn) {
      int col = n_base + wn * 64 + tn * 16 + (lane & 15);
#pragma unroll
      for (int i = 0; i < 4; ++i) {
        int row = m_base + wm * 64 + tm * 16 + (lane >> 4) * 4 + i;
        if (row < M)
          Cout[(size_t)row * ldc + col] = __float2bfloat16(acc[tm][tn][i]);
      }
    }
  }
}

// ---------------- LSTM pointwise (8 ch / thread, fast transcendentals) ----------------
__global__ __launch_bounds__(256) void lstm_kernel(const bf16* __restrict__ G, float* __restrict__ Cst,
                                                   bf16* __restrict__ Z, float* __restrict__ out,
                                                   const float* __restrict__ bias, const float* __restrict__ peep,
                                                   int t) {
  int idx = blockIdx.x * 256 + threadIdx.x;  // n*16 + c8
  int n = idx >> 4, c = (idx & 15) * 8;
  const bf16* g = G + (size_t)n * 512;
  bf16x8 gi = *(const bf16x8*)(g + c);
  bf16x8 gf = *(const bf16x8*)(g + 128 + c);
  bf16x8 gc = *(const bf16x8*)(g + 256 + c);
  bf16x8 go = *(const bf16x8*)(g + 384 + c);
  float cold[8];
  *(float4*)(cold)     = *(const float4*)(Cst + (size_t)n * 128 + c);
  *(float4*)(cold + 4) = *(const float4*)(Cst + (size_t)n * 128 + c + 4);
  float hv[8];
  float cn[8];
  union { bf16 h[8]; uint4 v; } oz;
#pragma unroll
  for (int j = 0; j < 8; ++j) {
    float Cold = cold[j];
    float ai = b2f(gi[j]) + bias[c + j]       + peep[c + j] * Cold;
    float af = b2f(gf[j]) + bias[128 + c + j] + peep[128 + c + j] * Cold;
    float ac = b2f(gc[j]) + bias[256 + c + j];
    float ao = b2f(go[j]) + bias[384 + c + j];
    float I = fsig(ai);
    float F = fsig(af);
    float Tc = ftanh(ac);
    float Cn = F * Cold + I * Tc;
    float O = fsig(ao + peep[256 + c + j] * Cn);
    float H = O * ftanh(Cn);
    cn[j] = Cn;
    hv[j] = H;
    oz.h[j] = __float2bfloat16(H);
  }
  *(float4*)(Cst + (size_t)n * 128 + c)     = *(const float4*)(cn);
  *(float4*)(Cst + (size_t)n * 128 + c + 4) = *(const float4*)(cn + 4);
  *(uint4*)(Z + (size_t)n * 768 + 384 + c) = oz.v;
  float* op = out + ((size_t)n * 4 + t) * 128 + c;
  *(float4*)(op)     = *(const float4*)(hv);
  *(float4*)(op + 4) = *(const float4*)(hv + 4);
}

extern "C" void kernel_launch(void* const* d_in, const int* in_sizes, int n_in,
                              void* d_out, int out_size, void* d_ws, size_t ws_size,
                              hipStream_t stream) {
  const float* X     = (const float*)d_in[0];
  const int*   edges = (const int*)d_in[1];
  const float* Wpool = (const float*)d_in[2];
  const float* convW = (const float*)d_in[3];
  const float* convB = (const float*)d_in[4];
  const float* peep  = (const float*)d_in[5];
  const float* gateB = (const float*)d_in[6];
  float* out = (float*)d_out;

  const int* src = edges;
  const int* dst = edges + EE;

  char* ws = (char*)d_ws;
  size_t off = 0;
  auto alloc = [&](size_t bytes) {
    void* p = ws + off;
    off += (bytes + 255) & ~(size_t)255;
    return p;
  };
  // Layout byte-identical to the round-5 PASSING kernel (no new top-level bufs).
  bf16*  WallT   = (bf16*) alloc((size_t)512 * 768 * 2);
  bf16*  WpoolBf = (bf16*) alloc((size_t)128 * 128 * 2);
  float* bias    = (float*)alloc(512 * 4);
  float* dinv    = (float*)alloc(NN * 4);
  int*   counts  = (int*)  alloc(NN * 4);
  int*   rowp    = (int*)  alloc((NN + 1) * 4);
  int*   cursor  = (int*)  alloc(NN * 4);
  int*   bsum    = (int*)  alloc(SCAN_NB * 4);
  uint2* edata   = (uint2*)alloc((size_t)EE * 8);
  float* Cst     = (float*)alloc((size_t)NN * 128 * 4);
  bf16*  Z       = (bf16*) alloc((size_t)NPAD * 768 * 2);
  bf16*  G       = (bf16*) alloc((size_t)NN * 512 * 2);

  // Overlays (zero extra workspace):
  int* perm  = cursor;          // cursor dead after fill_kernel; scan2 rewrites it each replay
  int* hist  = (int*)G;         // G first written by big GEMM inside t-loop (after degfill)
  int* rankc = (int*)G + DEGB;

  hipMemsetAsync(dinv, 0, NN * 4, stream);
  hipMemsetAsync(counts, 0, NN * 4, stream);
  hipMemsetAsync(hist, 0, 2 * DEGB * 4, stream);
  hipMemsetAsync(Cst, 0, (size_t)NN * 128 * 4, stream);

  prep_kernel<<<1667, 256, 0, stream>>>(convW, convB, gateB, Wpool, WallT, bias, WpoolBf);
  degcount_kernel<<<(EE + 255) / 256, 256, 0, stream>>>(src, dst, dinv, counts);
  dinv_kernel<<<(NN + 255) / 256, 256, 0, stream>>>(dinv);
  blocksum_kernel<<<SCAN_NB, 256, 0, stream>>>(counts, bsum);
  scan2_kernel<<<SCAN_NB, 1024, 0, stream>>>(counts, bsum, rowp, cursor);
  fill_kernel<<<(EE + 255) / 256, 256, 0, stream>>>(src, dst, dinv, cursor, edata);
  deghist_kernel<<<(NN + 255) / 256, 256, 0, stream>>>(counts, hist);
  degfill_kernel<<<(NN + 255) / 256, 256, 0, stream>>>(counts, hist, rankc, perm);
  zeroH_kernel<<<(NN * 16 + 255) / 256, 256, 0, stream>>>(Z);

  dim3 blk(256);
  for (int t = 0; t < TT; ++t) {
    // Xp = X_t @ Wpool^T -> Z[:,0:128]
    gemm_bt<1><<<dim3(391, 1), blk, 0, stream>>>(X + (size_t)t * NN * 128, 128,
                                                 WpoolBf, 128, Z, 768, NN, 128);
    // PXp (0->128), PH (384->512)
    prop_half<<<PROP_NG * 4, blk, 0, stream>>>(rowp, edata, perm, Z, 0, 128, -1, 384, 512, -1, 1.0f);
    // T2Xp = 2*P*PXp - Xp (128->256, base 0); T2H = 2*P*PH - H (512->640, base 384)
    prop_half<<<PROP_NG * 4, blk, 0, stream>>>(rowp, edata, perm, Z, 128, 256, 0, 512, 640, 384, 2.0f);
    // G[N,512] = Z[N,768] @ W_all
    gemm_bt<0><<<dim3(391, 4), blk, 0, stream>>>(Z, 768, WallT, 768, G, 512, NN, 768);
    // gates + cell update + output
    lstm_kernel<<<(NN * 16) / 256, blk, 0, stream>>>(G, Cst, Z, out, bias, peep, t);
  }
}

// Round 10
// 1122.348 us; speedup vs baseline: 1.2670x; 1.2670x over previous
//
#include <hip/hip_runtime.h>
#include <hip/hip_bf16.h>

#define NN 50000
#define EE 800000
#define TT 4
#define NPAD 50048         // 391*128, padded row count for async-LDS A loads
#define SCAN_NB 49         // ceil(50000/1024)
#define PROP_NG 1563       // ceil(50000/32)

typedef __hip_bfloat16 bf16;
typedef short bf16x8 __attribute__((ext_vector_type(8)));
typedef float f32x4 __attribute__((ext_vector_type(4)));

__device__ __forceinline__ void async_copy16(const void* g, void* l) {
  __builtin_amdgcn_global_load_lds((const __attribute__((address_space(1))) unsigned int*)g,
                                   (__attribute__((address_space(3))) unsigned int*)l,
                                   16, 0, 0);
}

__device__ __forceinline__ float b2f(short s) {
  return __uint_as_float(((unsigned)(unsigned short)s) << 16);
}

// fast sigmoid/tanh via v_exp_f32 (2^x) + v_rcp_f32.
// Saturation is clean: exp2->inf => rcp->0 (sig=0/tanh=-1); exp2->0 => rcp(1)=1.
__device__ __forceinline__ float fsig(float x) {
  float e = __builtin_amdgcn_exp2f(x * -1.442695041f);
  return __builtin_amdgcn_rcpf(1.f + e);
}
__device__ __forceinline__ float ftanh(float x) {
  float e = __builtin_amdgcn_exp2f(x * -2.885390082f);
  return fmaf(2.f, __builtin_amdgcn_rcpf(1.f + e), -1.f);
}

// ---------------- prep ----------------
// WallT [512][768] bf16. Columns nn = g*128+c (gate-group g, out-channel c).
// Rows k<384: X-BASIS (folded pool): W~[kch*128+f][c] -- built by wtilde_kernel.
// Rows k>=384: H-basis, direct copy of convW[(2g+1)][kch].
// Fused bias[512] fp32. (Wpool is folded away; no WpoolBf, no Xp-GEMM.)
__global__ void prep_kernel(const float* __restrict__ convW, const float* __restrict__ convB,
                            const float* __restrict__ gateB,
                            bf16* __restrict__ WallT, float* __restrict__ bias) {
  int idx = blockIdx.x * 256 + threadIdx.x;
  if (idx < 512 * 384) {
    int nn = idx / 384, k2 = idx % 384;
    int g = nn >> 7, c = nn & 127;
    int kch = k2 >> 7, r = k2 & 127;
    WallT[(size_t)nn * 768 + 384 + k2] =
        __float2bfloat16(convW[(((2 * g + 1) * 3 + kch) * 128 + r) * 128 + c]);
  } else if (idx < 512 * 384 + 512) {
    int n2 = idx - 512 * 384;
    int g = n2 >> 7, c = n2 & 127;
    bias[n2] = convB[(2 * g) * 128 + c] + convB[(2 * g + 1) * 128 + c] + gateB[g * 128 + c];
  }
}

// W~_kch = Wpool^T @ convW[2g][kch]  (prop commutes with the feature-dim
// right-multiply: Ti(P)(X Wpool^T) Wx = (Ti(P)X)(Wpool^T Wx) -- exact).
// W~[f][c] = sum_cin Wpool[cin][f] * convW[2g][kch][cin][c].
__global__ void wtilde_kernel(const float* __restrict__ convW, const float* __restrict__ Wpool,
                              bf16* __restrict__ WallT) {
  int idx = blockIdx.x * 256 + threadIdx.x;  // 512*384
  if (idx >= 512 * 384) return;
  int nn = idx / 384, kf = idx % 384;
  int g = nn >> 7, c = nn & 127;
  int kch = kf >> 7, f = kf & 127;
  const float* w = convW + (size_t)(((2 * g) * 3 + kch) * 128) * 128 + c;
  float s = 0.f;
#pragma unroll 4
  for (int cin = 0; cin < 128; ++cin)
    s += Wpool[cin * 128 + f] * w[cin * 128];
  WallT[(size_t)nn * 768 + kf] = __float2bfloat16(s);
}

// X_t (fp32) -> Z[:,0:128) bf16 (T0 of the X basis)
__global__ void castX_kernel(const float* __restrict__ X, bf16* __restrict__ Z) {
  int i = blockIdx.x * 256 + threadIdx.x;  // NN*16
  if (i >= NN * 16) return;
  int n = i >> 4, c = (i & 15) * 8;
  const float* x = X + (size_t)n * 128 + c;
  float4 a = *(const float4*)x;
  float4 b = *(const float4*)(x + 4);
  union { bf16 h[8]; uint4 v; } o;
  o.h[0] = __float2bfloat16(a.x); o.h[1] = __float2bfloat16(a.y);
  o.h[2] = __float2bfloat16(a.z); o.h[3] = __float2bfloat16(a.w);
  o.h[4] = __float2bfloat16(b.x); o.h[5] = __float2bfloat16(b.y);
  o.h[6] = __float2bfloat16(b.z); o.h[7] = __float2bfloat16(b.w);
  *(uint4*)(Z + (size_t)n * 768 + c) = o.v;
}

// ---------------- graph preprocessing ----------------
__global__ void degcount_kernel(const int* __restrict__ src, const int* __restrict__ dst,
                                float* __restrict__ deg, int* __restrict__ counts) {
  int e = blockIdx.x * 256 + threadIdx.x;
  if (e < EE) {
    atomicAdd(&deg[src[e]], 1.0f);
    atomicAdd(&counts[dst[e]], 1);
  }
}

__global__ void dinv_kernel(float* deg) {
  int n = blockIdx.x * 256 + threadIdx.x;
  if (n < NN) {
    float d = deg[n];
    deg[n] = (d > 0.f) ? rsqrtf(d) : 0.f;
  }
}

// partial sums: block b sums counts[b*1024 .. b*1024+1023]
__global__ void blocksum_kernel(const int* __restrict__ counts, int* __restrict__ bsum) {
  __shared__ int wsum2[4];
  int b = blockIdx.x, tid = threadIdx.x;
  int v = 0;
#pragma unroll
  for (int i = 0; i < 4; ++i) {
    int idx = b * 1024 + tid + i * 256;
    v += (idx < NN) ? counts[idx] : 0;
  }
#pragma unroll
  for (int off = 32; off; off >>= 1) v += __shfl_down(v, off);
  if ((tid & 63) == 0) wsum2[tid >> 6] = v;
  __syncthreads();
  if (tid == 0) bsum[b] = wsum2[0] + wsum2[1] + wsum2[2] + wsum2[3];
}

// full scan: each block re-reads the 49 block sums, scans its own 1024 chunk
__global__ void scan2_kernel(const int* __restrict__ counts, const int* __restrict__ bsum,
                             int* __restrict__ row_ptr, int* __restrict__ cursor) {
  __shared__ int wsum[16];
  int b = blockIdx.x, tid = threadIdx.x;
  int lane = tid & 63, wv = tid >> 6;
  int boff = 0, total = 0;
  for (int i = 0; i < SCAN_NB; ++i) {
    int s = bsum[i];
    if (i < b) boff += s;
    total += s;
  }
  int idx = b * 1024 + tid;
  int v = (idx < NN) ? counts[idx] : 0;
  int sc = v;
#pragma unroll
  for (int off = 1; off < 64; off <<= 1) {
    int t = __shfl_up(sc, off);
    if (lane >= off) sc += t;
  }
  if (lane == 63) wsum[wv] = sc;
  __syncthreads();
  if (wv == 0) {
    int w = (lane < 16) ? wsum[lane] : 0;
#pragma unroll
    for (int off = 1; off < 16; off <<= 1) {
      int t = __shfl_up(w, off);
      if (lane >= off) w += t;
    }
    if (lane < 16) wsum[lane] = w;
  }
  __syncthreads();
  int excl = boff + sc - v + (wv ? wsum[wv - 1] : 0);
  if (idx < NN) { row_ptr[idx] = excl; cursor[idx] = excl; }
  if (b == 0 && tid == 0) row_ptr[NN] = total;
}

// pack (src, weight) per edge into uint2
__global__ void fill_kernel(const int* __restrict__ src, const int* __restrict__ dst,
                            const float* __restrict__ dinv, int* __restrict__ cursor,
                            uint2* __restrict__ edata) {
  int e = blockIdx.x * 256 + threadIdx.x;
  if (e < EE) {
    int s = src[e], d = dst[e];
    float w = -(dinv[s] * dinv[d]);
    int pos = atomicAdd(&cursor[d], 1);
    uint2 v;
    v.x = (unsigned)s;
    v.y = __float_as_uint(w);
    edata[pos] = v;
  }
}

// zero the H window Z[:,384:512)
__global__ void zeroH_kernel(bf16* __restrict__ Z) {
  int i = blockIdx.x * 256 + threadIdx.x;
  if (i < NN * 16) {
    int n = i >> 4, c = i & 15;
    *(uint4*)(Z + (size_t)n * 768 + 384 + c * 8) = make_uint4(0u, 0u, 0u, 0u);
  }
}

// ---------------- prop: out = scale * (P @ in) - base ----------------
__device__ __forceinline__ void accum8(float* acc, uint4 z, float w) {
  float f0 = __uint_as_float(z.x << 16);
  float f1 = __uint_as_float(z.x & 0xffff0000u);
  float f2 = __uint_as_float(z.y << 16);
  float f3 = __uint_as_float(z.y & 0xffff0000u);
  float f4 = __uint_as_float(z.z << 16);
  float f5 = __uint_as_float(z.z & 0xffff0000u);
  float f6 = __uint_as_float(z.w << 16);
  float f7 = __uint_as_float(z.w & 0xffff0000u);
  acc[0] = fmaf(w, f0, acc[0]);
  acc[1] = fmaf(w, f1, acc[1]);
  acc[2] = fmaf(w, f2, acc[2]);
  acc[3] = fmaf(w, f3, acc[3]);
  acc[4] = fmaf(w, f4, acc[4]);
  acc[5] = fmaf(w, f5, acc[5]);
  acc[6] = fmaf(w, f6, acc[6]);
  acc[7] = fmaf(w, f7, acc[7]);
}

// Half-split prop (round-5 proven form): subtask = bid&3 = (window, 64ch-half).
// 8 lanes x 16B = 128B per edge gather = one full L2 line per request.
// At ~65us/launch this is the XCD-replication compulsory-miss floor
// (~205MB fills at the ~3.1TB/s random-line service rate). Degree-sort (r9)
// refuted: prop delta +3us/launch, sort prep cost 270us. Natural node order.
__global__ __launch_bounds__(256) void prop_half(const int* __restrict__ row_ptr,
                                                 const uint2* __restrict__ edata,
                                                 bf16* __restrict__ Z,
                                                 int in_offA, int out_offA, int baseA,
                                                 int in_offB, int out_offB, int baseB,
                                                 float scale) {
  const int bid = blockIdx.x;
  const int st = bid & 3;
  const int half = st & 1;
  const int grp = st >> 1;
  const int in_off  = (grp ? in_offB  : in_offA) + half * 64;
  const int out_off = (grp ? out_offB : out_offA) + half * 64;
  const int base    = grp ? baseB : baseA;
  const int tid = threadIdx.x;
  const int node = (bid >> 2) * 32 + (tid >> 3);
  const int lane = tid & 7;
  if (node >= NN) return;
  const int e0 = row_ptr[node], e1 = row_ptr[node + 1];
  float acc[8] = {0.f, 0.f, 0.f, 0.f, 0.f, 0.f, 0.f, 0.f};
  const bf16* zin = Z + in_off + lane * 8;
  int e = e0;
  for (; e + 4 <= e1; e += 4) {
    uint2 d0 = edata[e];
    uint2 d1 = edata[e + 1];
    uint2 d2 = edata[e + 2];
    uint2 d3 = edata[e + 3];
    uint4 z0 = *(const uint4*)(zin + (size_t)d0.x * 768);
    uint4 z1 = *(const uint4*)(zin + (size_t)d1.x * 768);
    uint4 z2 = *(const uint4*)(zin + (size_t)d2.x * 768);
    uint4 z3 = *(const uint4*)(zin + (size_t)d3.x * 768);
    accum8(acc, z0, __uint_as_float(d0.y));
    accum8(acc, z1, __uint_as_float(d1.y));
    accum8(acc, z2, __uint_as_float(d2.y));
    accum8(acc, z3, __uint_as_float(d3.y));
  }
  for (; e < e1; ++e) {
    uint2 d = edata[e];
    uint4 z = *(const uint4*)(zin + (size_t)d.x * 768);
    accum8(acc, z, __uint_as_float(d.y));
  }
  float bv[8] = {0.f, 0.f, 0.f, 0.f, 0.f, 0.f, 0.f, 0.f};
  if (base >= 0) {
    uint4 b = *(const uint4*)(Z + (size_t)node * 768 + base + half * 64 + lane * 8);
    bv[0] = __uint_as_float(b.x << 16);
    bv[1] = __uint_as_float(b.x & 0xffff0000u);
    bv[2] = __uint_as_float(b.y << 16);
    bv[3] = __uint_as_float(b.y & 0xffff0000u);
    bv[4] = __uint_as_float(b.z << 16);
    bv[5] = __uint_as_float(b.z & 0xffff0000u);
    bv[6] = __uint_as_float(b.w << 16);
    bv[7] = __uint_as_float(b.w & 0xffff0000u);
  }
  union {
    bf16 h[8];
    uint4 v;
  } o;
#pragma unroll
  for (int j = 0; j < 8; ++j)
    o.h[j] = __float2bfloat16(fmaf(scale, acc[j], -bv[j]));
  *(uint4*)(Z + (size_t)node * 768 + out_off + lane * 8) = o.v;
}

// ---------------- GEMM: C[M,Nc] = A[M,K] @ Bt[Nc,K]^T, fp32 acc ----------------
// 2-PHASE double-buffered: stage tile it+1 into buf^1 BEFORE computing tile it;
// ONE __syncthreads per K-step. Measured r5: 79us, MfmaUtil 19% -- the
// 2-barrier family's structural ceiling.
// Flat LDS tiles (128 rows x 32 bf16), XOR-swizzled 16B chunks:
// chunk (row r, kseg s) at chunk index r*4 + (s ^ ((r>>1)&3)).
__global__ __launch_bounds__(256) void gemm_bt(const bf16* __restrict__ Ain, int lda,
                                               const bf16* __restrict__ Bt, int ldbt,
                                               bf16* __restrict__ Cout, int ldc,
                                               int M, int K) {
  __shared__ __align__(16) bf16 As[2][128 * 32];
  __shared__ __align__(16) bf16 Bs[2][128 * 32];
  const int tid = threadIdx.x;
  const int lane = tid & 63, wid = tid >> 6;
  const int wm = wid >> 1, wn = wid & 1;
  const int m_base = blockIdx.x * 128;
  const int n_base = blockIdx.y * 128;
  f32x4 acc[4][4] = {};

  // staging chunks c0 = tid, c1 = tid + 256; r = c>>2, p = c&3, s = p ^ ((r>>1)&3)
  const int r0 = tid >> 2, p = tid & 3;
  const int r1 = r0 + 64;
  const int s0 = p ^ ((r0 >> 1) & 3);
  const int s1 = p ^ ((r1 >> 1) & 3);

  const bf16* Ag0 = Ain + (size_t)(m_base + r0) * lda + s0 * 8;
  const bf16* Ag1 = Ain + (size_t)(m_base + r1) * lda + s1 * 8;
  const bf16* Bg0 = Bt + (size_t)(n_base + r0) * ldbt + s0 * 8;
  const bf16* Bg1 = Bt + (size_t)(n_base + r1) * ldbt + s1 * 8;

  auto stageA = [&](bf16* dst) {
    async_copy16(Ag0, dst + wid * 512);
    async_copy16(Ag1, dst + 2048 + wid * 512);
    Ag0 += 32; Ag1 += 32;
  };
  auto stageB = [&](bf16* dst) {
    async_copy16(Bg0, dst + wid * 512);
    async_copy16(Bg1, dst + 2048 + wid * 512);
    Bg0 += 32; Bg1 += 32;
  };

  // fragment LDS elem offsets, fixed per lane
  int offA[4], offB[4];
  const int sq = lane >> 4;
#pragma unroll
  for (int tm = 0; tm < 4; ++tm) {
    int r = wm * 64 + tm * 16 + (lane & 15);
    offA[tm] = r * 32 + (sq ^ ((r >> 1) & 3)) * 8;
  }
#pragma unroll
  for (int tn = 0; tn < 4; ++tn) {
    int r = wn * 64 + tn * 16 + (lane & 15);
    offB[tn] = r * 32 + (sq ^ ((r >> 1) & 3)) * 8;
  }

  const int nk = K >> 5;

  stageA(As[0]);
  stageB(Bs[0]);
  __syncthreads();

  for (int it = 0; it < nk; ++it) {
    const bf16* Ac = As[it & 1];
    const bf16* Bc = Bs[it & 1];
    if (it + 1 < nk) {
      stageA(As[(it + 1) & 1]);
      stageB(Bs[(it + 1) & 1]);
    }

    bf16x8 af[4], bfr[4];
#pragma unroll
    for (int tm = 0; tm < 4; ++tm) af[tm] = *(const bf16x8*)(Ac + offA[tm]);
#pragma unroll
    for (int tn = 0; tn < 4; ++tn) bfr[tn] = *(const bf16x8*)(Bc + offB[tn]);
#pragma unroll
    for (int tm = 0; tm < 4; ++tm)
#pragma unroll
      for (int tn = 0; tn < 4; ++tn)
        acc[tm][tn] = __builtin_amdgcn_mfma_f32_16x16x32_bf16(af[tm], bfr[tn], acc[tm][tn], 0, 0, 0);

    __syncthreads();
  }

  // C/D layout: col = lane&15, row = (lane>>4)*4 + i  [m89/m91 verified]
#pragma unroll
  for (int tm = 0; tm < 4; ++tm) {
#pragma unroll
    for (int tn = 0; tn < 4; ++tn) {
      int col = n_base + wn * 64 + tn * 16 + (lane & 15);
#pragma unroll
      for (int i = 0; i < 4; ++i) {
        int row = m_base + wm * 64 + tm * 16 + (lane >> 4) * 4 + i;
        if (row < M)
          Cout[(size_t)row * ldc + col] = __float2bfloat16(acc[tm][tn][i]);
      }
    }
  }
}

// ---------------- LSTM pointwise (8 ch / thread, fast transcendentals) ----------------
__global__ __launch_bounds__(256) void lstm_kernel(const bf16* __restrict__ G, float* __restrict__ Cst,
                                                   bf16* __restrict__ Z, float* __restrict__ out,
                                                   const float* __restrict__ bias, const float* __restrict__ peep,
                                                   int t) {
  int idx = blockIdx.x * 256 + threadIdx.x;  // n*16 + c8
  int n = idx >> 4, c = (idx & 15) * 8;
  const bf16* g = G + (size_t)n * 512;
  bf16x8 gi = *(const bf16x8*)(g + c);
  bf16x8 gf = *(const bf16x8*)(g + 128 + c);
  bf16x8 gc = *(const bf16x8*)(g + 256 + c);
  bf16x8 go = *(const bf16x8*)(g + 384 + c);
  float cold[8];
  *(float4*)(cold)     = *(const float4*)(Cst + (size_t)n * 128 + c);
  *(float4*)(cold + 4) = *(const float4*)(Cst + (size_t)n * 128 + c + 4);
  float hv[8];
  float cn[8];
  union { bf16 h[8]; uint4 v; } oz;
#pragma unroll
  for (int j = 0; j < 8; ++j) {
    float Cold = cold[j];
    float ai = b2f(gi[j]) + bias[c + j]       + peep[c + j] * Cold;
    float af = b2f(gf[j]) + bias[128 + c + j] + peep[128 + c + j] * Cold;
    float ac = b2f(gc[j]) + bias[256 + c + j];
    float ao = b2f(go[j]) + bias[384 + c + j];
    float I = fsig(ai);
    float F = fsig(af);
    float Tc = ftanh(ac);
    float Cn = F * Cold + I * Tc;
    float O = fsig(ao + peep[256 + c + j] * Cn);
    float H = O * ftanh(Cn);
    cn[j] = Cn;
    hv[j] = H;
    oz.h[j] = __float2bfloat16(H);
  }
  *(float4*)(Cst + (size_t)n * 128 + c)     = *(const float4*)(cn);
  *(float4*)(Cst + (size_t)n * 128 + c + 4) = *(const float4*)(cn + 4);
  *(uint4*)(Z + (size_t)n * 768 + 384 + c) = oz.v;
  float* op = out + ((size_t)n * 4 + t) * 128 + c;
  *(float4*)(op)     = *(const float4*)(hv);
  *(float4*)(op + 4) = *(const float4*)(hv + 4);
}

extern "C" void kernel_launch(void* const* d_in, const int* in_sizes, int n_in,
                              void* d_out, int out_size, void* d_ws, size_t ws_size,
                              hipStream_t stream) {
  const float* X     = (const float*)d_in[0];
  const int*   edges = (const int*)d_in[1];
  const float* Wpool = (const float*)d_in[2];
  const float* convW = (const float*)d_in[3];
  const float* convB = (const float*)d_in[4];
  const float* peep  = (const float*)d_in[5];
  const float* gateB = (const float*)d_in[6];
  float* out = (float*)d_out;

  const int* src = edges;
  const int* dst = edges + EE;

  char* ws = (char*)d_ws;
  size_t off = 0;
  auto alloc = [&](size_t bytes) {
    void* p = ws + off;
    off += (bytes + 255) & ~(size_t)255;
    return p;
  };
  bf16*  WallT   = (bf16*) alloc((size_t)512 * 768 * 2);
  float* bias    = (float*)alloc(512 * 4);
  float* dinv    = (float*)alloc(NN * 4);
  int*   counts  = (int*)  alloc(NN * 4);
  int*   rowp    = (int*)  alloc((NN + 1) * 4);
  int*   cursor  = (int*)  alloc(NN * 4);
  int*   bsum    = (int*)  alloc(SCAN_NB * 4);
  uint2* edata   = (uint2*)alloc((size_t)EE * 8);
  float* Cst     = (float*)alloc((size_t)NN * 128 * 4);
  bf16*  Z       = (bf16*) alloc((size_t)NPAD * 768 * 2);
  bf16*  G       = (bf16*) alloc((size_t)NN * 512 * 2);

  hipMemsetAsync(dinv, 0, NN * 4, stream);
  hipMemsetAsync(counts, 0, NN * 4, stream);
  hipMemsetAsync(Cst, 0, (size_t)NN * 128 * 4, stream);

  prep_kernel<<<(512 * 384 + 512 + 255) / 256, 256, 0, stream>>>(convW, convB, gateB, WallT, bias);
  wtilde_kernel<<<(512 * 384 + 255) / 256, 256, 0, stream>>>(convW, Wpool, WallT);
  degcount_kernel<<<(EE + 255) / 256, 256, 0, stream>>>(src, dst, dinv, counts);
  dinv_kernel<<<(NN + 255) / 256, 256, 0, stream>>>(dinv);
  blocksum_kernel<<<SCAN_NB, 256, 0, stream>>>(counts, bsum);
  scan2_kernel<<<SCAN_NB, 1024, 0, stream>>>(counts, bsum, rowp, cursor);
  fill_kernel<<<(EE + 255) / 256, 256, 0, stream>>>(src, dst, dinv, cursor, edata);
  zeroH_kernel<<<(NN * 16 + 255) / 256, 256, 0, stream>>>(Z);

  dim3 blk(256);
  for (int t = 0; t < TT; ++t) {
    // T0x = bf16(X_t) -> Z[:,0:128]  (Wpool folded into WallT's X-basis rows)
    castX_kernel<<<(NN * 16 + 255) / 256, blk, 0, stream>>>(X + (size_t)t * NN * 128, Z);
    // PX (0->128), PH (384->512)
    prop_half<<<PROP_NG * 4, blk, 0, stream>>>(rowp, edata, Z, 0, 128, -1, 384, 512, -1, 1.0f);
    // T2x = 2*P*PX - X (128->256, base 0); T2h = 2*P*PH - H (512->640, base 384)
    prop_half<<<PROP_NG * 4, blk, 0, stream>>>(rowp, edata, Z, 128, 256, 0, 512, 640, 384, 2.0f);
    // G[N,512] = Z[N,768] @ W_all
    gemm_bt<<<dim3(391, 4), blk, 0, stream>>>(Z, 768, WallT, 768, G, 512, NN, 768);
    // gates + cell update + output
    lstm_kernel<<<(NN * 16) / 256, blk, 0, stream>>>(G, Cst, Z, out, bias, peep, t);
  }
}